// Round 9
// baseline (207.580 us; speedup 1.0000x reference)
//
#include <hip/hip_runtime.h>

typedef __attribute__((ext_vector_type(8))) short short8;
typedef __attribute__((ext_vector_type(4))) float f32x4;

#define NROWS 32768        // B*H*W
#define NELEM 262144       // B*C*H*W
#define KCB   8192
#define ROWS_PB 64
#define NWAVE 8            // k-waves per block; each scans KCB/8 = 1024 entries

// round-to-nearest-even fp32 -> bf16 (finite values only)
static __device__ __forceinline__ short to_bf16(float x) {
    unsigned u = __float_as_uint(x);
    unsigned r = (u + 0x7FFFu + ((u >> 16) & 1u)) >> 16;
    return (short)r;
}

// Prep: pack codebook entries as 16 bf16 [e0..e7, -0.5*||e||^2, 0...],
// pack z rows as 8 bf16, zero the loss slot.
__global__ __launch_bounds__(256) void vq_prep(
    const float* __restrict__ z, const float* __restrict__ cb,
    short8* __restrict__ cbb, short8* __restrict__ pka, float* __restrict__ out)
{
    int gid = blockIdx.x * 256 + threadIdx.x;
    if (gid == 0) out[NELEM] = 0.0f;
    if (gid < KCB) {
        const float4* p = (const float4*)(cb + (size_t)gid * 8);
        float4 a = p[0], b = p[1];
        float h = -0.5f * (a.x*a.x + a.y*a.y + a.z*a.z + a.w*a.w
                         + b.x*b.x + b.y*b.y + b.z*b.z + b.w*b.w);
        short8 lo = { to_bf16(a.x), to_bf16(a.y), to_bf16(a.z), to_bf16(a.w),
                      to_bf16(b.x), to_bf16(b.y), to_bf16(b.z), to_bf16(b.w) };
        short8 hi = { to_bf16(h), 0, 0, 0, 0, 0, 0, 0 };
        cbb[2 * gid]     = lo;
        cbb[2 * gid + 1] = hi;
    } else {
        int n = gid - KCB;
        int bb = n >> 12, hw = n & 4095;
        const float* zp = z + (size_t)bb * 32768 + hw;
        short8 v = { to_bf16(zp[0]),     to_bf16(zp[4096]),
                     to_bf16(zp[8192]),  to_bf16(zp[12288]),
                     to_bf16(zp[16384]), to_bf16(zp[20480]),
                     to_bf16(zp[24576]), to_bf16(zp[28672]) };
        pka[n] = v;
    }
}

// liveness pins (rule #17: prevent DCE of ablated consumers)
static __device__ __forceinline__ void keepf4(const f32x4& v) {
    asm volatile("" :: "v"(v[0]), "v"(v[1]), "v"(v[2]), "v"(v[3]));
}
static __device__ __forceinline__ void keeps8(const short8& v) {
    int4 u;
    __builtin_memcpy(&u, &v, 16);
    asm volatile("" :: "v"(u.x), "v"(u.y), "v"(u.z), "v"(u.w));
}

// Exact round-3 structure (best: 33.6 us total, VGPR 52, no spill), templated:
// MODE 0: full scan + argmax + emit (per rep; loss scaled 1/REP -> idempotent)
// MODE 1: loads + MFMA only (acc kept live; no pack/max, no emit)
// MODE 2: loads only (B-frags kept live)
template<int MODE, int REP>
__global__ __launch_bounds__(512, 4) void vq_scan_t(
    const float* __restrict__ z, const float* __restrict__ cb,
    const short8* __restrict__ cbb, const short8* __restrict__ pka,
    float* __restrict__ out)
{
    __shared__ float sbest[NWAVE][ROWS_PB];
    __shared__ float lsum[NWAVE];

    const int tid  = threadIdx.x;
    const int lane = tid & 63;
    const int w    = tid >> 6;        // k-wave 0..7
    const int col  = lane & 15;
    const int g    = lane >> 4;

    const int row0 = blockIdx.x * ROWS_PB;

    // A fragments: 4 row-tiles of 16; k-slots 0..7 = channels, 8 = 1.0
    short8 af[4];
    #pragma unroll
    for (int f = 0; f < 4; ++f) {
        short8 v = {0, 0, 0, 0, 0, 0, 0, 0};
        if (g == 0)      v = pka[row0 + f * 16 + col];
        else if (g == 1) v[0] = (short)0x3F80;   // bf16(1.0) pairs with -0.5||e||^2
        af[f] = v;
    }

    const int kbase = w * 1024;
    const char* bpc0 = (const char*)cbb + (size_t)(kbase + col) * 32
                                        + (size_t)(g & 1) * 16;
    const unsigned inv0 = (unsigned)(8191 - (kbase + col));
    const f32x4 zacc = {0.f, 0.f, 0.f, 0.f};

    for (int rep = 0; rep < REP; ++rep) {
        unsigned lz = 0;
        asm volatile("" : "+v"(lz));             // launder: defeat cross-rep CSE
        const char* bp = bpc0 + lz;

        float best[4][4];
        if constexpr (MODE == 0) {
            #pragma unroll
            for (int f = 0; f < 4; ++f)
                #pragma unroll
                for (int r = 0; r < 4; ++r)
                    best[f][r] = __uint_as_float(0xFF800000u);   // -inf
        }

        #pragma unroll 4
        for (int t = 0; t < 64; ++t) {           // 64 tiles x 16 entries
            short8 bf = *(const short8*)(bp + (size_t)t * 512);
            if constexpr (MODE == 2) {
                keeps8(bf);
            } else {
                const unsigned iv = inv0 - (unsigned)(t * 16);
                #pragma unroll
                for (int f = 0; f < 4; ++f) {
                    f32x4 acc = __builtin_amdgcn_mfma_f32_16x16x32_bf16(af[f], bf, zacc, 0, 0, 0);
                    if constexpr (MODE == 1) {
                        keepf4(acc);
                    } else {
                        #pragma unroll
                        for (int r = 0; r < 4; ++r) {
                            float p = __uint_as_float((__float_as_uint(acc[r]) & 0xFFFFE000u) | iv);
                            best[f][r] = fmaxf(best[f][r], p);
                        }
                    }
                }
            }
        }

        if constexpr (MODE == 0) {
            // cross-lane max within each 16-lane col group
            #pragma unroll
            for (int d = 1; d < 16; d <<= 1)
                #pragma unroll
                for (int f = 0; f < 4; ++f)
                    #pragma unroll
                    for (int r = 0; r < 4; ++r)
                        best[f][r] = fmaxf(best[f][r], __shfl_xor(best[f][r], d));

            if (col == 0) {
                #pragma unroll
                for (int f = 0; f < 4; ++f)
                    #pragma unroll
                    for (int r = 0; r < 4; ++r)
                        sbest[w][f * 16 + g * 4 + r] = best[f][r];
            }
            __syncthreads();

            // emit: 64 rows x 8 ch, one elem/thread
            const int pos = tid & 63;
            const int ch  = tid >> 6;
            float m = sbest[0][pos];
            #pragma unroll
            for (int kw = 1; kw < NWAVE; ++kw) m = fmaxf(m, sbest[kw][pos]);
            const int k = 8191 - (int)(__float_as_uint(m) & 8191u);

            const int n = row0 + pos;
            const size_t o = ((size_t)(n >> 12)) * 32768 + (size_t)ch * 4096
                           + (size_t)(n & 4095);
            float ev = cb[(size_t)k * 8 + ch];
            float zz = z[o];
            out[o] = ev;
            float dd = ev - zz;
            float sq = dd * dd;
            #pragma unroll
            for (int off = 32; off > 0; off >>= 1) sq += __shfl_down(sq, off);
            if (lane == 0) lsum[w] = sq;
            __syncthreads();
            if (tid == 0) {
                float s = 0.f;
                #pragma unroll
                for (int kw = 0; kw < NWAVE; ++kw) s += lsum[kw];
                atomicAdd(out + NELEM, s * (1.25f / (float)NELEM / (float)REP));
            }
            __syncthreads();   // protect sbest/lsum before next rep rewrites
        }
    }
}

extern "C" void kernel_launch(void* const* d_in, const int* in_sizes, int n_in,
                              void* d_out, int out_size, void* d_ws, size_t ws_size,
                              hipStream_t stream)
{
    const float* z  = (const float*)d_in[0];   // [8, 8, 64, 64] fp32
    const float* cb = (const float*)d_in[1];   // [8192, 8] fp32
    float* out = (float*)d_out;                // 262144 z_q + 1 loss
    short8* cbb = (short8*)d_ws;                       // 256 KB packed codebook
    short8* pka = (short8*)((char*)d_ws + 256 * 1024); // 512 KB packed z rows

    vq_prep<<<(KCB + NROWS) / 256, 256, 0, stream>>>(z, cb, cbb, pka, out);
    // MODE0: real work (x3 reps -> visible in top-5 over the 39us fills)
    vq_scan_t<0, 3><<<NROWS / ROWS_PB, 512, 0, stream>>>(z, cb, cbb, pka, out);
    // MODE1: loads+MFMA only (x8); MODE2: loads only (x8) -- ablation probes
    vq_scan_t<1, 8><<<NROWS / ROWS_PB, 512, 0, stream>>>(z, cb, cbb, pka, out);
    vq_scan_t<2, 8><<<NROWS / ROWS_PB, 512, 0, stream>>>(z, cb, cbb, pka, out);
}

// Round 10
// 35.649 us; speedup vs baseline: 5.8228x; 5.8228x over previous
//
#include <hip/hip_runtime.h>

typedef __attribute__((ext_vector_type(8))) short short8;
typedef __attribute__((ext_vector_type(16))) float f32x16;

#define NROWS 32768        // B*H*W
#define NELEM 262144       // B*C*H*W
#define KCB   8192
#define ROWS_PB 32         // rows per block (one 32-row MFMA tile)
#define NWAVE 8            // k-waves per block; each scans KCB/8 = 1024 entries

// round-to-nearest-even fp32 -> bf16 (finite values only)
static __device__ __forceinline__ short to_bf16(float x) {
    unsigned u = __float_as_uint(x);
    unsigned r = (u + 0x7FFFu + ((u >> 16) & 1u)) >> 16;
    return (short)r;
}

// Prep (R8-verified layout): codebook group g (32 entries) = 1KB:
// bytes [0,512) = entries' ch0..7 (16B each, k=0..7),
// bytes [512,1024) = entries' [-0.5*||e||^2, 0 x7] (k=8..15).
// Also pack z rows (8 bf16) and zero the loss slot.
__global__ __launch_bounds__(256) void vq_prep(
    const float* __restrict__ z, const float* __restrict__ cb,
    short8* __restrict__ cbb32, short8* __restrict__ pka, float* __restrict__ out)
{
    int gid = blockIdx.x * 256 + threadIdx.x;
    if (gid == 0) out[NELEM] = 0.0f;
    if (gid < KCB) {
        const float4* p = (const float4*)(cb + (size_t)gid * 8);
        float4 a = p[0], b = p[1];
        float h = -0.5f * (a.x*a.x + a.y*a.y + a.z*a.z + a.w*a.w
                         + b.x*b.x + b.y*b.y + b.z*b.z + b.w*b.w);
        short8 lo = { to_bf16(a.x), to_bf16(a.y), to_bf16(a.z), to_bf16(a.w),
                      to_bf16(b.x), to_bf16(b.y), to_bf16(b.z), to_bf16(b.w) };
        short8 hi = { to_bf16(h), 0, 0, 0, 0, 0, 0, 0 };
        cbb32[(gid >> 5) * 64 + (gid & 31)]      = lo;
        cbb32[(gid >> 5) * 64 + 32 + (gid & 31)] = hi;
    } else {
        int n = gid - KCB;
        int bb = n >> 12, hw = n & 4095;
        const float* zp = z + (size_t)bb * 32768 + hw;
        short8 v = { to_bf16(zp[0]),     to_bf16(zp[4096]),
                     to_bf16(zp[8192]),  to_bf16(zp[12288]),
                     to_bf16(zp[16384]), to_bf16(zp[20480]),
                     to_bf16(zp[24576]), to_bf16(zp[28672]) };
        pka[n] = v;
    }
}

// guaranteed 3-inst pack+merge: p0=(s0&M)|iv0, p1=(s1&M)|iv1, best=max3(p0,p1,best)
static __device__ __forceinline__ void packmax3(float& best, float s0, float s1,
                                                unsigned iv0, unsigned iv1)
{
    float p0, p1;
    asm("v_and_or_b32 %0, %1, %2, %3"
        : "=v"(p0) : "v"(s0), "s"(0xFFFFE000u), "v"(iv0));
    asm("v_and_or_b32 %0, %1, %2, %3"
        : "=v"(p1) : "v"(s1), "s"(0xFFFFE000u), "v"(iv1));
    asm("v_max3_f32 %0, %1, %2, %0"
        : "+v"(best) : "v"(p0), "v"(p1));
}

// Scan: 1024 blocks x 512 thr (8 k-waves), 32 rows/block. Wave w scans its
// private 1024-entry slice as 16 tile-PAIRS (2x32 entries): direct global->
// VGPR loads, 2x mfma_f32_32x32x16_bf16 (1024 scores each), 48 VALU pack/max.
// ~85 VGPR -> 6 waves/SIMD. Fused combine + gather + z_q + loss epilogue.
__global__ __launch_bounds__(512, 4) void vq_scan32(
    const float* __restrict__ z, const float* __restrict__ cb,
    const short8* __restrict__ cbb32, const short8* __restrict__ pka,
    float* __restrict__ out)
{
    __shared__ float sbest[NWAVE][ROWS_PB];
    __shared__ float lsum[NWAVE];

    const int tid  = threadIdx.x;
    const int lane = tid & 63;
    const int w    = tid >> 6;            // k-wave 0..7
    const int c32  = lane & 31;
    const int hi   = lane >> 5;

    const int row0 = blockIdx.x * ROWS_PB;

    // ---- A frag (R8-verified): lanes 0..31 = row channels (k=0..7);
    //      lanes 32..63 = [1.0, 0...] (k=8 pairs with -0.5||e||^2) ----
    short8 af;
    if (hi == 0) {
        af = pka[row0 + c32];
    } else {
        short8 one = {(short)0x3F80, 0, 0, 0, 0, 0, 0, 0};
        af = one;
    }

    const int kbase = w * (KCB / NWAVE);  // 1024 entries
    const char* bpc = (const char*)cbb32 + (size_t)kbase * 32
                    + (size_t)c32 * 16 + (size_t)hi * 512;

    float best[16];
    #pragma unroll
    for (int r = 0; r < 16; ++r)
        best[r] = __uint_as_float(0xFF800000u);   // -inf

    const unsigned inv0 = 8191u - (unsigned)kbase - (unsigned)c32;
    const f32x16 z16 = {0.f,0.f,0.f,0.f,0.f,0.f,0.f,0.f,
                        0.f,0.f,0.f,0.f,0.f,0.f,0.f,0.f};

    // ---- 16 pairs x 64 entries ----
    #pragma unroll 4
    for (int pr = 0; pr < 16; ++pr) {
        const char* p = bpc + (size_t)pr * 2048;
        short8 b0 = *(const short8*)(p);
        short8 b1 = *(const short8*)(p + 1024);
        f32x16 d0 = __builtin_amdgcn_mfma_f32_32x32x16_bf16(af, b0, z16, 0, 0, 0);
        f32x16 d1 = __builtin_amdgcn_mfma_f32_32x32x16_bf16(af, b1, z16, 0, 0, 0);
        const unsigned iv0 = inv0 - (unsigned)(pr * 64);
        const unsigned iv1 = iv0 - 32u;
        #pragma unroll
        for (int r = 0; r < 16; ++r)
            packmax3(best[r], d0[r], d1[r], iv0, iv1);
    }

    // ---- reduce over 32 entry-cols (lanes 0..31 / 32..63 hold distinct rows) ----
    #pragma unroll
    for (int d = 1; d < 32; d <<= 1)
        #pragma unroll
        for (int r = 0; r < 16; ++r)
            best[r] = fmaxf(best[r], __shfl_xor(best[r], d));

    if (c32 == 0) {
        #pragma unroll
        for (int r = 0; r < 16; ++r) {
            const int m = (r & 3) + ((r >> 2) << 3) + (hi << 2);  // C/D row map (R8-verified)
            sbest[w][m] = best[r];
        }
    }
    __syncthreads();

    // ---- emit: 32 rows x 8 ch, one elem/thread (first 256 threads) ----
    float sq = 0.0f;
    if (tid < 256) {
        const int pos = tid & 31;
        const int ch  = tid >> 5;
        float m = sbest[0][pos];
        #pragma unroll
        for (int kw = 1; kw < NWAVE; ++kw) m = fmaxf(m, sbest[kw][pos]);
        const int k = 8191 - (int)(__float_as_uint(m) & 8191u);

        const int n = row0 + pos;
        const size_t o = ((size_t)(n >> 12)) * 32768 + (size_t)ch * 4096
                       + (size_t)(n & 4095);
        float ev = cb[(size_t)k * 8 + ch];
        float zz = z[o];
        out[o] = ev;
        float dd = ev - zz;
        sq = dd * dd;
    }
    #pragma unroll
    for (int off = 32; off > 0; off >>= 1) sq += __shfl_down(sq, off);
    if (lane == 0) lsum[w] = sq;
    __syncthreads();
    if (tid == 0) {
        float s = 0.f;
        #pragma unroll
        for (int kw = 0; kw < NWAVE; ++kw) s += lsum[kw];
        atomicAdd(out + NELEM, s * (1.25f / (float)NELEM));
    }
}

extern "C" void kernel_launch(void* const* d_in, const int* in_sizes, int n_in,
                              void* d_out, int out_size, void* d_ws, size_t ws_size,
                              hipStream_t stream)
{
    const float* z  = (const float*)d_in[0];   // [8, 8, 64, 64] fp32
    const float* cb = (const float*)d_in[1];   // [8192, 8] fp32
    float* out = (float*)d_out;                // 262144 z_q + 1 loss
    short8* cbb32 = (short8*)d_ws;                       // 256 KB packed codebook
    short8* pka   = (short8*)((char*)d_ws + 256 * 1024); // 512 KB packed z rows

    vq_prep<<<(KCB + NROWS) / 256, 256, 0, stream>>>(z, cb, cbb32, pka, out);
    vq_scan32<<<NROWS / ROWS_PB, 512, 0, stream>>>(z, cb, cbb32, pka, out);
}

// Round 11
// 33.561 us; speedup vs baseline: 6.1851x; 1.0622x over previous
//
#include <hip/hip_runtime.h>

typedef __attribute__((ext_vector_type(8))) short short8;
typedef __attribute__((ext_vector_type(16))) float f32x16;

#define NROWS 32768        // B*H*W
#define NELEM 262144       // B*C*H*W
#define KCB   8192
#define ROWS_PB 32         // rows per block (one 32-row MFMA tile)
#define NWAVE 8            // k-waves per block; each scans KCB/8 = 1024 entries

// round-to-nearest-even fp32 -> bf16 (finite values only)
static __device__ __forceinline__ short to_bf16(float x) {
    unsigned u = __float_as_uint(x);
    unsigned r = (u + 0x7FFFu + ((u >> 16) & 1u)) >> 16;
    return (short)r;
}

// Prep (R8/R10-verified layout): codebook group g (32 entries) = 1KB:
// bytes [0,512) = entries' ch0..7 (16B each, k=0..7),
// bytes [512,1024) = entries' [-0.5*||e||^2, 0 x7] (k=8..15).
// Also pack z rows (8 bf16) and zero the loss slot.
__global__ __launch_bounds__(256) void vq_prep(
    const float* __restrict__ z, const float* __restrict__ cb,
    short8* __restrict__ cbb32, short8* __restrict__ pka, float* __restrict__ out)
{
    int gid = blockIdx.x * 256 + threadIdx.x;
    if (gid == 0) out[NELEM] = 0.0f;
    if (gid < KCB) {
        const float4* p = (const float4*)(cb + (size_t)gid * 8);
        float4 a = p[0], b = p[1];
        float h = -0.5f * (a.x*a.x + a.y*a.y + a.z*a.z + a.w*a.w
                         + b.x*b.x + b.y*b.y + b.z*b.z + b.w*b.w);
        short8 lo = { to_bf16(a.x), to_bf16(a.y), to_bf16(a.z), to_bf16(a.w),
                      to_bf16(b.x), to_bf16(b.y), to_bf16(b.z), to_bf16(b.w) };
        short8 hi = { to_bf16(h), 0, 0, 0, 0, 0, 0, 0 };
        cbb32[(gid >> 5) * 64 + (gid & 31)]      = lo;
        cbb32[(gid >> 5) * 64 + 32 + (gid & 31)] = hi;
    } else {
        int n = gid - KCB;
        int bb = n >> 12, hw = n & 4095;
        const float* zp = z + (size_t)bb * 32768 + hw;
        short8 v = { to_bf16(zp[0]),     to_bf16(zp[4096]),
                     to_bf16(zp[8192]),  to_bf16(zp[12288]),
                     to_bf16(zp[16384]), to_bf16(zp[20480]),
                     to_bf16(zp[24576]), to_bf16(zp[28672]) };
        pka[n] = v;
    }
}

// 3-inst pack+merge: best = max3((s0&M)|iv0, (s1&M)|iv1, best)
static __device__ __forceinline__ void packmax3(float& best, float s0, float s1,
                                                unsigned iv0, unsigned iv1)
{
    float p0, p1;
    asm("v_and_or_b32 %0, %1, %2, %3"
        : "=v"(p0) : "v"(s0), "s"(0xFFFFE000u), "v"(iv0));
    asm("v_and_or_b32 %0, %1, %2, %3"
        : "=v"(p1) : "v"(s1), "s"(0xFFFFE000u), "v"(iv1));
    asm("v_max3_f32 %0, %1, %2, %0"
        : "+v"(best) : "v"(p0), "v"(p1));
}

// Scan: 1024 blocks x 512 thr (8 k-waves), 32 rows/block, 32x32x16 MFMA.
// Explicit 2-slot in-wave pipeline: pair p+1's MFMAs issue BEFORE packing
// pair p (pack's ~100 VALU cyc hides MFMA result latency); buffers refilled
// right after consumption. Named regs + unroll 1 -> ~112 VGPR, no spill.
__global__ __launch_bounds__(512, 4) void vq_scan32(
    const float* __restrict__ z, const float* __restrict__ cb,
    const short8* __restrict__ cbb32, const short8* __restrict__ pka,
    float* __restrict__ out)
{
    __shared__ float sbest[NWAVE][ROWS_PB];
    __shared__ float lsum[NWAVE];

    const int tid  = threadIdx.x;
    const int lane = tid & 63;
    const int w    = tid >> 6;            // k-wave 0..7
    const int c32  = lane & 31;
    const int hi   = lane >> 5;

    const int row0 = blockIdx.x * ROWS_PB;

    // A frag: lanes 0..31 = row channels (k=0..7); lanes 32..63 = [1.0,0...] (k=8)
    short8 af;
    if (hi == 0) {
        af = pka[row0 + c32];
    } else {
        short8 one = {(short)0x3F80, 0, 0, 0, 0, 0, 0, 0};
        af = one;
    }

    const int kbase = w * (KCB / NWAVE);  // 1024 entries = 16 pairs of groups
    const char* bpc = (const char*)cbb32 + (size_t)kbase * 32
                    + (size_t)c32 * 16 + (size_t)hi * 512;

    float best[16];
    #pragma unroll
    for (int r = 0; r < 16; ++r)
        best[r] = __uint_as_float(0xFF800000u);   // -inf

    const f32x16 z16 = {0.f,0.f,0.f,0.f,0.f,0.f,0.f,0.f,
                        0.f,0.f,0.f,0.f,0.f,0.f,0.f,0.f};

#define LDP0(P) (*(const short8*)(bpc + (size_t)(P) * 2048))
#define LDP1(P) (*(const short8*)(bpc + (size_t)(P) * 2048 + 1024))
#define PACK16(D0, D1, IV)                                            \
    {   const unsigned iv0_ = (IV), iv1_ = (IV) - 32u;                \
        _Pragma("unroll")                                             \
        for (int r = 0; r < 16; ++r)                                  \
            packmax3(best[r], (D0)[r], (D1)[r], iv0_, iv1_);          }

    unsigned ivA = 8191u - (unsigned)kbase - (unsigned)c32;  // pair 0 base
    unsigned ivB = ivA - 64u;                                // pair 1 base

    // ---- prologue ----
    short8 bA0 = LDP0(0), bA1 = LDP1(0);
    short8 bB0 = LDP0(1), bB1 = LDP1(1);
    f32x16 dA0 = __builtin_amdgcn_mfma_f32_32x32x16_bf16(af, bA0, z16, 0, 0, 0);
    f32x16 dA1 = __builtin_amdgcn_mfma_f32_32x32x16_bf16(af, bA1, z16, 0, 0, 0);
    bA0 = LDP0(2); bA1 = LDP1(2);

    // ---- steady state: i handles pack(2i) and pack(2i+1) ----
    #pragma unroll 1
    for (int i = 0; i < 7; ++i) {
        f32x16 dB0 = __builtin_amdgcn_mfma_f32_32x32x16_bf16(af, bB0, z16, 0, 0, 0);
        f32x16 dB1 = __builtin_amdgcn_mfma_f32_32x32x16_bf16(af, bB1, z16, 0, 0, 0);
        bB0 = LDP0(2 * i + 3); bB1 = LDP1(2 * i + 3);
        PACK16(dA0, dA1, ivA);                 // covers dB latency
        ivA -= 128u;
        dA0 = __builtin_amdgcn_mfma_f32_32x32x16_bf16(af, bA0, z16, 0, 0, 0);
        dA1 = __builtin_amdgcn_mfma_f32_32x32x16_bf16(af, bA1, z16, 0, 0, 0);
        {   const int pn = (2 * i + 4) & 15;   // i=6 wraps -> dead load, harmless
            bA0 = LDP0(pn); bA1 = LDP1(pn); }
        PACK16(dB0, dB1, ivB);                 // covers dA latency
        ivB -= 128u;
    }

    // ---- epilogue: pairs 14 (in dA) and 15 (bB) ----
    {
        f32x16 dB0 = __builtin_amdgcn_mfma_f32_32x32x16_bf16(af, bB0, z16, 0, 0, 0);
        f32x16 dB1 = __builtin_amdgcn_mfma_f32_32x32x16_bf16(af, bB1, z16, 0, 0, 0);
        PACK16(dA0, dA1, ivA);
        PACK16(dB0, dB1, ivB);
    }

    // ---- reduce over 32 entry-cols ----
    #pragma unroll
    for (int d = 1; d < 32; d <<= 1)
        #pragma unroll
        for (int r = 0; r < 16; ++r)
            best[r] = fmaxf(best[r], __shfl_xor(best[r], d));

    if (c32 == 0) {
        #pragma unroll
        for (int r = 0; r < 16; ++r) {
            const int m = (r & 3) + ((r >> 2) << 3) + (hi << 2);  // C/D row map (verified)
            sbest[w][m] = best[r];
        }
    }
    __syncthreads();

    // ---- emit: 32 rows x 8 ch, one elem/thread (first 256 threads) ----
    float sq = 0.0f;
    if (tid < 256) {
        const int pos = tid & 31;
        const int ch  = tid >> 5;
        float m = sbest[0][pos];
        #pragma unroll
        for (int kw = 1; kw < NWAVE; ++kw) m = fmaxf(m, sbest[kw][pos]);
        const int k = 8191 - (int)(__float_as_uint(m) & 8191u);

        const int n = row0 + pos;
        const size_t o = ((size_t)(n >> 12)) * 32768 + (size_t)ch * 4096
                       + (size_t)(n & 4095);
        float ev = cb[(size_t)k * 8 + ch];
        float zz = z[o];
        out[o] = ev;
        float dd = ev - zz;
        sq = dd * dd;
    }
    #pragma unroll
    for (int off = 32; off > 0; off >>= 1) sq += __shfl_down(sq, off);
    if (lane == 0) lsum[w] = sq;
    __syncthreads();
    if (tid == 0) {
        float s = 0.f;
        #pragma unroll
        for (int kw = 0; kw < NWAVE; ++kw) s += lsum[kw];
        atomicAdd(out + NELEM, s * (1.25f / (float)NELEM));
    }
}

extern "C" void kernel_launch(void* const* d_in, const int* in_sizes, int n_in,
                              void* d_out, int out_size, void* d_ws, size_t ws_size,
                              hipStream_t stream)
{
    const float* z  = (const float*)d_in[0];   // [8, 8, 64, 64] fp32
    const float* cb = (const float*)d_in[1];   // [8192, 8] fp32
    float* out = (float*)d_out;                // 262144 z_q + 1 loss
    short8* cbb32 = (short8*)d_ws;                       // 256 KB packed codebook
    short8* pka   = (short8*)((char*)d_ws + 256 * 1024); // 512 KB packed z rows

    vq_prep<<<(KCB + NROWS) / 256, 256, 0, stream>>>(z, cb, cbb32, pka, out);
    vq_scan32<<<NROWS / ROWS_PB, 512, 0, stream>>>(z, cb, cbb32, pka, out);
}